// Round 10
// baseline (674.995 us; speedup 1.0000x reference)
//
#include <hip/hip_runtime.h>
#include <cstdint>
#include <cstddef>

// CTC-CRF logZ forward: S=1024, NZ=5, linear-domain, damped pow2 renorm.
// R9 (32 consumers + 2 near-helpers/batch warming L2) = 640us, -16% vs the
// 762us per-CU HBM-streaming pin -> warming mechanism CONFIRMED (MSHR
// occupancy: line throughput ~ MSHR/latency). This round scales it:
//   tier-1 NEAR (2/batch): L3->L2 of consumer's XCD, window 32 steps
//     (4 consumers/XCD x 32 x 20KB = 2.56MB < 4MB L2), poll sleep ~512cyc.
//   tier-2 FAR (3/batch, 96 blocks): HBM->L3, rolling [p+32, p+320] window
//     (~184MB < 256MB LLC), nontemporal loads to limit L2 pollution.
// Grid 192, all blocks carry the 84KB LDS pad -> 1 block/CU guaranteed,
// no co-residency with consumers. Consumers never wait (fallback = R9).

#define NB 32
#define SD 1024
#define CD 5120
#define AHEAD 32
#define CHUNK 8
#define FCHUNK 32
#define FAR_W 320
#define DONE_S 0x7fffffff

typedef float f4a __attribute__((ext_vector_type(4), aligned(4)));

__device__ __forceinline__ float fexp2(float x) { return __builtin_amdgcn_exp2f(x); }
__device__ __forceinline__ float flog2(float x) { return __builtin_amdgcn_logf(x); }

template <int CTRL>
__device__ __forceinline__ float dppq(float v) {
  return __int_as_float(
      __builtin_amdgcn_update_dpp(0, __float_as_int(v), CTRL, 0xF, 0xF, true));
}

__global__ void init_prog(int* prog) {
  const int i = threadIdx.x;
  if (i < NB) prog[i * 64] = 0;
}

__global__ void __launch_bounds__(1024) ctc_logz(const float* __restrict__ scores,
                                                 float* __restrict__ out,
                                                 int* __restrict__ prog, int T) {
  __shared__ float ap[2 * SD];
  __shared__ float red[16];
  __shared__ float pad[19456];   // 76KB pad -> >80KB total -> 1 block/CU
  __shared__ int pmsg;

  const int bid = blockIdx.x;
  const int u = threadIdx.x;
  if (T < 0) { pad[u] = 1.f; out[0] = pad[u ^ 1]; }  // keep pad allocated

  const size_t tstr = (size_t)NB * CD;

  if (bid >= NB) {
    // --------------------------- helper paths ---------------------------
    const int h = bid - NB;
    const int n = h & 31;          // batch (near tier: same XCD mod-8)
    const int role = h >> 5;       // 0,1 = near ; 2,3,4 = far
    const float* base = scores + (size_t)n * CD;
    float acc = 0.f;

    if (role < 2) {
      // near: L3 -> consumer-XCD L2, chunks of 8 steps, parity split
      for (int c = role; c * CHUNK < T; c += 2) {
        const int t0 = c * CHUNK;
        int p;
        for (;;) {
          if (u == 0)
            pmsg = __hip_atomic_load(&prog[n * 64], __ATOMIC_RELAXED,
                                     __HIP_MEMORY_SCOPE_AGENT);
          __syncthreads();
          p = pmsg;
          __syncthreads();
          if (p == DONE_S || t0 < p + AHEAD) break;
          __builtin_amdgcn_s_sleep(8);    // ~512 cyc
        }
        if (p == DONE_S) break;
        if (t0 + CHUNK <= p) continue;
        if (u < 320) {                    // 320 x 64B lines = one 20KB step
          const float* cb = base + (size_t)t0 * tstr + (size_t)u * 16;
          const int lim = (T - t0 < CHUNK) ? (T - t0) : CHUNK;
          for (int s = 0; s < lim; ++s) { acc += *cb; cb += tstr; }
        }
      }
    } else {
      // far: HBM -> L3, chunks of 32 steps, 3-way split, window [p+32,p+320]
      for (int c = role - 2; c * FCHUNK < T; c += 3) {
        const int t0 = c * FCHUNK;
        int p;
        for (;;) {
          if (u == 0)
            pmsg = __hip_atomic_load(&prog[n * 64], __ATOMIC_RELAXED,
                                     __HIP_MEMORY_SCOPE_AGENT);
          __syncthreads();
          p = pmsg;
          __syncthreads();
          if (p == DONE_S || t0 < p + FAR_W) break;
          __builtin_amdgcn_s_sleep(64);   // ~4096 cyc
        }
        if (p == DONE_S) break;
        if (t0 + FCHUNK <= p) continue;
        if (u < 320) {
          const float* cb = base + (size_t)t0 * tstr + (size_t)u * 16;
          const int lim = (T - t0 < FCHUNK) ? (T - t0) : FCHUNK;
          for (int s = 0; s < lim; ++s) {
            acc += __builtin_nontemporal_load(cb);
            cb += tstr;
          }
        }
      }
    }
    asm volatile("" ::"v"(acc));        // DCE sink
    return;
  }

  // ------------------------- consumer path (R7/R9) -----------------------
  const int n = bid;
  const int lane = u & 63;
  const int wid = u >> 6;
  const int p = u >> 2, c = u & 3;
  const int rdoff = (c << 8) | (p ^ (c << 3));   // slot(p + 256c), swizzled
  const int wroff = u ^ ((u & 0x300) >> 5);      // slot(u)

  ap[u] = 1.f; ap[SD + u] = 1.f;
  float a_cur = 1.f;
  float nLf = 0.f;
  int Lnext = 0, cacc = 0;

  const float K = 1.44269504088896340736f;
  const float LN2 = 0.69314718055994530942f;

  const float* sn = scores + (size_t)n * CD + (size_t)u * 5;
  const size_t str4 = 4 * tstr;

  auto CP = [&](int t, const f4a& qa, float qb) {
    const int rb = ((t + 1) & 1) * SD;
    const float vr = ap[rb + rdoff];    // pred read, conflict-free
    const float R = ap[rb];             // uniform addr -> broadcast
    const float p0 = dppq<0x00>(vr);    // A[p]
    const float p1 = dppq<0x55>(vr);    // A[256+p]
    const float p2 = dppq<0xAA>(vr);    // A[512+p]
    const float p3 = dppq<0xFF>(vr);    // A[768+p]
    float e0 = fexp2(__builtin_fmaf(qa.x, K, nLf));
    float e1 = fexp2(__builtin_fmaf(qa.y, K, nLf));
    float e2 = fexp2(__builtin_fmaf(qa.z, K, nLf));
    float e3 = fexp2(__builtin_fmaf(qa.w, K, nLf));
    float e4 = fexp2(__builtin_fmaf(qb,   K, nLf));
    float s = e0 * a_cur;
    s = __builtin_fmaf(e1, p0, s);
    s = __builtin_fmaf(e2, p1, s);
    s = __builtin_fmaf(e3, p2, s);
    s = __builtin_fmaf(e4, p3, s);
    a_cur = s;
    cacc += Lnext;
    ap[(t & 1) * SD + wroff] = s;
    const int xb = ((__float_as_int(R) >> 23) & 0xFF) - 127;
    Lnext = xb >> 2;                    // damped controller: lag 1, gain 1/4
    nLf = (float)(-Lnext);
    if (((t & 3) == 0) && (u == 0))     // publish progress for helpers
      __hip_atomic_store(&prog[n * 64], t, __ATOMIC_RELAXED,
                         __HIP_MEMORY_SCOPE_AGENT);
    asm volatile("s_waitcnt lgkmcnt(0)\n\ts_barrier" ::: "memory");
  };

#define PRO(cc)                                                             \
  const float* P##cc = sn + (size_t)((cc) < T ? (cc) : T - 1) * tstr;       \
  f4a qa##cc = *(const f4a*)P##cc;                                          \
  float qb##cc = P##cc[4];                                                  \
  P##cc += str4;
  PRO(0) PRO(1) PRO(2) PRO(3)
#undef PRO

  __syncthreads();

#define RL(cc)                                                              \
  qa##cc = *(const f4a*)P##cc;                                              \
  qb##cc = P##cc[4];                                                        \
  P##cc += str4;

  int t = 0;
  for (; t + 8 <= T; t += 4) {
    CP(t + 0, qa0, qb0); RL(0)
    CP(t + 1, qa1, qb1); RL(1)
    CP(t + 2, qa2, qb2); RL(2)
    CP(t + 3, qa3, qb3); RL(3)
  }
#undef RL

#define EPI1(cc)                                                            \
  if (t + (cc) < T) {                                                       \
    CP(t + (cc), qa##cc, qb##cc);                                           \
    if (t + 4 + (cc) < T) { qa##cc = *(const f4a*)P##cc; qb##cc = P##cc[4]; }\
  }
  EPI1(0) EPI1(1) EPI1(2) EPI1(3)
#undef EPI1
  t += 4;
#define EPI2(cc) if (t + (cc) < T) CP(t + (cc), qa##cc, qb##cc);
  EPI2(0) EPI2(1) EPI2(2) EPI2(3)
#undef EPI2

  if (u == 0)
    __hip_atomic_store(&prog[n * 64], DONE_S, __ATOMIC_RELAXED,
                       __HIP_MEMORY_SCOPE_AGENT);

  float v = a_cur;
#pragma unroll
  for (int d = 1; d < 64; d <<= 1) v += __shfl_xor(v, d, 64);
  if (lane == 0) red[wid] = v;
  __syncthreads();
  if (u == 0) {
    float ssum = red[0];
#pragma unroll
    for (int i = 1; i < 16; ++i) ssum += red[i];
    out[n] = LN2 * ((float)cacc + flog2(ssum));
  }
}

extern "C" void kernel_launch(void* const* d_in, const int* in_sizes, int n_in,
                              void* d_out, int out_size, void* d_ws, size_t ws_size,
                              hipStream_t stream) {
  const float* scores = (const float*)d_in[0];
  float* out = (float*)d_out;
  int* prog = (int*)d_ws;
  const long long tot = (long long)in_sizes[0];
  const int T = (int)(tot / ((long long)NB * CD));
  init_prog<<<dim3(1), dim3(64), 0, stream>>>(prog);
  ctc_logz<<<dim3(192), dim3(1024), 0, stream>>>(scores, out, prog, T);
}